// Round 5
// baseline (11548.788 us; speedup 1.0000x reference)
//
#include <hip/hip_runtime.h>
#include <cstdint>
#include <cstddef>

#define BATCH  8192
#define INDIM  64
#define OUTDIM 64
#define HID    128
#define BT     32          // samples per block
#define NT     1024        // 16 waves: wq = w&7 (n-quad), mh = w>>3 (m-half)
#define KP2    584         // 64 x | 128 h0[0] | 128 h0[1] | 128 h1[0] | 128 h1[1] | 8 pad
#define KB0    6           // 192/32 k-blocks layer0
#define KB1    8           // 256/32 k-blocks layer1
#define KBD    4           // 128/32 k-blocks decoder

#define XH0(p) (64 + 128 * (p))
#define XH1(p) (320 + 128 * (p))

// packed ws layout (same as previous rounds; prepack unchanged). u16 region:
#define W0U    0           // 32nt x 6kb x 2term x 512 = 196608 u16
#define W1U    196608      // 32nt x 8kb x 2term x 512 = 262144 u16
#define WDU    458752      // 4nt  x 4kb x 2term x 512 = 16384 u16
// float region (float index into ws):
#define B0F    237568      // 512 f32 (permuted, bih0+bhh0)
#define B1F    238080      // 512 f32
#define BDF    238592      // 64 f32
#define NPACK  238656

typedef unsigned short u16;
typedef __attribute__((ext_vector_type(8))) short bfrag;   // 8 bf16 = 4 VGPR (MFMA A/B)
typedef __attribute__((ext_vector_type(4))) float facc;    // 4 f32  (MFMA C/D 16x16)

__device__ __forceinline__ u16 f2bf(float x) {
  uint32_t u = __float_as_uint(x);
  return (u16)((u + 0x7fffu + ((u >> 16) & 1u)) >> 16);   // RNE
}
__device__ __forceinline__ float bf2f(u16 h) {
  return __uint_as_float(((uint32_t)h) << 16);
}
__device__ __forceinline__ float fsig(float x) { return 1.0f / (1.0f + __expf(-x)); }
__device__ __forceinline__ float ftanh(float x) {
  float e = __expf(2.0f * x);
  return 1.0f - 2.0f / (e + 1.0f);
}
__device__ __forceinline__ facc splat4(float v) {
  facc a; a[0] = v; a[1] = v; a[2] = v; a[3] = v; return a;
}

// LDS-only barrier: drains ds ops but NOT vmcnt, so global weight/x prefetches
// stay in flight across phase boundaries. All cross-wave hazards are LDS.
__device__ __forceinline__ void bar_lds() {
  __builtin_amdgcn_sched_barrier(0);
  asm volatile("s_waitcnt lgkmcnt(0)" ::: "memory");
  __builtin_amdgcn_s_barrier();
  __builtin_amdgcn_sched_barrier(0);
}

// One GEMM over KB k-blocks; A columns come from two segments:
// k-blocks [0,SPLIT) at off1, [SPLIT,KB) at off2 (parity-dependent h columns).
// Single-buffered weight fragments; latency covered by 4 waves/SIMD TLP.
template <int KB, int SPLIT>
__device__ __forceinline__ void gemm_run(const u16* __restrict__ wt,
                                         const u16 (&Hhi)[BT][KP2],
                                         const u16 (&Hlo)[BT][KP2],
                                         int off1, int off2,
                                         int c, int g, int mh, int ntq,
                                         facc (&acc)[4]) {
#pragma unroll
  for (int kb = 0; kb < KB; ++kb) {
    bfrag wf[8];
#pragma unroll
    for (int tt = 0; tt < 4; ++tt) {
      const u16* p = wt + (((ntq + tt) * KB + kb) * 2) * 512;
      wf[tt * 2]     = *(const bfrag*)p;            // 1KB coalesced per wave
      wf[tt * 2 + 1] = *(const bfrag*)(p + 512);
    }
    const int colA = ((kb < SPLIT) ? off1 + kb * 32
                                   : off2 + (kb - SPLIT) * 32) + g * 8;
    const bfrag ah = *(const bfrag*)&Hhi[mh * 16 + c][colA];   // ds_read_b128
    const bfrag al = *(const bfrag*)&Hlo[mh * 16 + c][colA];
    __builtin_amdgcn_s_setprio(1);
#pragma unroll
    for (int tt = 0; tt < 4; ++tt) {
      facc a = acc[tt];
      a = __builtin_amdgcn_mfma_f32_16x16x32_bf16(ah, wf[tt * 2],     a, 0, 0, 0);
      a = __builtin_amdgcn_mfma_f32_16x16x32_bf16(ah, wf[tt * 2 + 1], a, 0, 0, 0);
      a = __builtin_amdgcn_mfma_f32_16x16x32_bf16(al, wf[tt * 2],     a, 0, 0, 0);
      acc[tt] = a;
    }
    __builtin_amdgcn_s_setprio(0);
  }
}

__global__ __launch_bounds__(NT, 1) void lstm_kernel(
    const float* __restrict__ x, const void* __restrict__ pkv,
    float* __restrict__ out, int S, int P) {
  // A = [x | h0(par0) | h0(par1) | h1(par0) | h1(par1)] bf16 hi/lo, [sample][col]
  __shared__ __align__(16) u16 Ahi[BT][KP2];
  __shared__ __align__(16) u16 Alo[BT][KP2];

  const u16* pku = (const u16*)pkv;
  const float* pkf = (const float*)pkv;

  const int tid = threadIdx.x;
  const int lane = tid & 63;
  const int w = tid >> 6;        // 0..15
  const int wq = w & 7;          // n-quad: gate types 0..3 of unit group wq
  const int mh = w >> 3;         // m-half: rows mh*16 .. mh*16+15
  const int c = lane & 15;
  const int g = lane >> 4;
  const int ntq = wq * 4;
  const int b0 = blockIdx.x * BT;
  const int jcol = wq * 16 + c;  // hidden unit owned by this thread

  for (int i = tid; i < BT * KP2; i += NT) {
    (&Ahi[0][0])[i] = 0;
    (&Alo[0][0])[i] = 0;
  }

  float b0r[4], b1r[4];
#pragma unroll
  for (int t = 0; t < 4; ++t) {
    b0r[t] = pkf[B0F + (ntq + t) * 16 + c];
    b1r[t] = pkf[B1F + (ntq + t) * 16 + c];
  }
  const int ntd = w & 3, mtd = (w >> 2) & 1;   // decoder tile (waves 0..7 only)
  const float bdr = pkf[BDF + ntd * 16 + c];

  float c0r[4], c1r[4];          // cell state for unit jcol, rows mh*16+g*4+r
#pragma unroll
  for (int q = 0; q < 4; ++q) { c0r[q] = 0.f; c1r[q] = 0.f; }

  const u16* w0t = pku + W0U + lane * 8;
  const u16* w1t = pku + W1U + lane * 8;
  const u16* wdt = pku + WDU + lane * 8;

  // stage x(0), prefetch x(1). Threads 0..511 own one float4 of the 32x64 tile.
  const int sx = tid >> 4, cx = (tid & 15) * 4;
  float4 xr = make_float4(0.f, 0.f, 0.f, 0.f);
  if (tid < 512) {
    const float4 v = *(const float4*)(x + (size_t)(b0 + sx) * S * INDIM + cx);
    float vv[4] = {v.x, v.y, v.z, v.w};
#pragma unroll
    for (int q = 0; q < 4; ++q) {
      u16 hh = f2bf(vv[q]);
      Ahi[sx][cx + q] = hh;
      Alo[sx][cx + q] = f2bf(vv[q] - bf2f(hh));
    }
    if (S > 1) xr = *(const float4*)(x + ((size_t)(b0 + sx) * S + 1) * INDIM + cx);
  }

  bar_lds();   // init + x(0) visible

  int par = 0;
  const int T = S + P;
  for (int step = 0; step < T; ++step) {
    // ---------------- layer 0: x [0,64) + h0[par] ----------------
    facc acc[4];
#pragma unroll
    for (int t = 0; t < 4; ++t) acc[t] = splat4(b0r[t]);
    gemm_run<KB0, 2>(w0t, Ahi, Alo, 0, XH0(par), c, g, mh, ntq, acc);
    bar_lds();   // B_a: all GEMM0 reads (x, h0[par]) done

    // ep0 -> h0[!par] (columns nobody is reading)
    {
      const int col0 = XH0(par ^ 1) + jcol;
#pragma unroll
      for (int r = 0; r < 4; ++r) {
        float gi = fsig(acc[0][r]);
        float gf = fsig(acc[1][r]);
        float gg = ftanh(acc[2][r]);
        float go = fsig(acc[3][r]);
        float cn = fmaf(gf, c0r[r], gi * gg);
        c0r[r] = cn;
        float hv = go * ftanh(cn);
        const int s = mh * 16 + g * 4 + r;
        u16 hh = f2bf(hv);
        Ahi[s][col0] = hh;
        Alo[s][col0] = f2bf(hv - bf2f(hh));
      }
    }
    // stage x(step+1) (x cols are dead: GEMM0 done, GEMM1 doesn't read them)
    if (tid < 512) {
      if (step + 1 < S) {
        float vv[4] = {xr.x, xr.y, xr.z, xr.w};
#pragma unroll
        for (int q = 0; q < 4; ++q) {
          u16 hh = f2bf(vv[q]);
          Ahi[sx][cx + q] = hh;
          Alo[sx][cx + q] = f2bf(vv[q] - bf2f(hh));
        }
      }
      if (step + 2 < S)
        xr = *(const float4*)(x + ((size_t)(b0 + sx) * S + step + 2) * INDIM + cx);
    }
    bar_lds();   // B_b: h0[!par] + x(step+1) visible

    // ---------------- layer 1: h0[!par] + h1[par] ----------------
#pragma unroll
    for (int t = 0; t < 4; ++t) acc[t] = splat4(b1r[t]);
    gemm_run<KB1, 4>(w1t, Ahi, Alo, XH0(par ^ 1), XH1(par), c, g, mh, ntq, acc);

    // ep1 -> h1[!par]; no barrier needed before next GEMM0 (disjoint columns),
    // B_a of step+1 makes it visible before GEMM1(t+1) reads it.
    {
      const int col1 = XH1(par ^ 1) + jcol;
#pragma unroll
      for (int r = 0; r < 4; ++r) {
        float gi = fsig(acc[0][r]);
        float gf = fsig(acc[1][r]);
        float gg = ftanh(acc[2][r]);
        float go = fsig(acc[3][r]);
        float cn = fmaf(gf, c1r[r], gi * gg);
        c1r[r] = cn;
        float hv = go * ftanh(cn);
        const int s = mh * 16 + g * 4 + r;
        u16 hh = f2bf(hv);
        Ahi[s][col1] = hh;
        Alo[s][col1] = f2bf(hv - bf2f(hh));
      }
    }

    // ---------------- decoder (waves 0..7) + feedback ----------------
    if (step >= S) {
      bfrag wdf[8];
      if (w < 8) {
#pragma unroll
        for (int kb = 0; kb < KBD; ++kb) {
          const u16* p = wdt + ((ntd * KBD + kb) * 2) * 512;
          wdf[kb * 2]     = *(const bfrag*)p;
          wdf[kb * 2 + 1] = *(const bfrag*)(p + 512);
        }
      }
      bar_lds();   // B_c: h1[!par] visible
      if (w < 8) {
        facc da = splat4(bdr);
#pragma unroll
        for (int kb = 0; kb < KBD; ++kb) {
          const int colA = XH1(par ^ 1) + kb * 32 + g * 8;
          const bfrag dah = *(const bfrag*)&Ahi[mtd * 16 + c][colA];
          const bfrag dal = *(const bfrag*)&Alo[mtd * 16 + c][colA];
          da = __builtin_amdgcn_mfma_f32_16x16x32_bf16(dah, wdf[kb * 2],     da, 0, 0, 0);
          da = __builtin_amdgcn_mfma_f32_16x16x32_bf16(dah, wdf[kb * 2 + 1], da, 0, 0, 0);
          da = __builtin_amdgcn_mfma_f32_16x16x32_bf16(dal, wdf[kb * 2],     da, 0, 0, 0);
        }
        const int dstep = step - S;
#pragma unroll
        for (int r = 0; r < 4; ++r) {
          const int s = mtd * 16 + g * 4 + r;
          const int o = ntd * 16 + c;
          float pv = da[r];
          out[((size_t)(b0 + s) * P + dstep) * OUTDIM + o] = pv;
          u16 hh = f2bf(pv);                 // feedback -> next step's input cols
          Ahi[s][o] = hh;
          Alo[s][o] = f2bf(pv - bf2f(hh));
        }
      }
      bar_lds();   // B_d: feedback visible before GEMM0(t+1)
    }
    par ^= 1;
  }
}

// Pack weights into MFMA-fragment order, bf16 hi/lo; biases permuted + pre-summed.
// Gate permutation: packed n = ug*64 + t*16 + u  <->  torch row = t*128 + ug*16 + u
// Fragment: value at [nt][kb][term][lane][j] = W[k = kb*32 + (lane>>4)*8 + j][gate nt*16 + (lane&15)]
__global__ void prepack_kernel(const float* __restrict__ wih0, const float* __restrict__ whh0,
                               const float* __restrict__ bih0, const float* __restrict__ bhh0,
                               const float* __restrict__ wih1, const float* __restrict__ whh1,
                               const float* __restrict__ bih1, const float* __restrict__ bhh1,
                               const float* __restrict__ wdec, const float* __restrict__ bdec,
                               void* __restrict__ pko) {
  int idx = blockIdx.x * blockDim.x + threadIdx.x;
  if (idx >= NPACK) return;
  u16* pu = (u16*)pko;
  float* pf = (float*)pko;
  if (idx < 98304) {                       // W0: 32nt * 6kb * 512
    int nt = idx / 3072, rem = idx % 3072;
    int kb = rem >> 9, q = rem & 511, ln = q >> 3, j = q & 7;
    int n = nt * 16 + (ln & 15);
    int row = ((n >> 4) & 3) * HID + (n >> 6) * 16 + (n & 15);
    int k = kb * 32 + (ln >> 4) * 8 + j;
    float wv = (k < INDIM) ? wih0[row * INDIM + k] : whh0[row * HID + k - INDIM];
    u16 hi = f2bf(wv), lo = f2bf(wv - bf2f(hi));
    int base = W0U + ((nt * KB0 + kb) * 2) * 512;
    pu[base + q] = hi;
    pu[base + 512 + q] = lo;
  } else if (idx < 229376) {               // W1: 32nt * 8kb * 512
    int r = idx - 98304;
    int nt = r >> 12, rem = r & 4095;
    int kb = rem >> 9, q = rem & 511, ln = q >> 3, j = q & 7;
    int n = nt * 16 + (ln & 15);
    int row = ((n >> 4) & 3) * HID + (n >> 6) * 16 + (n & 15);
    int k = kb * 32 + (ln >> 4) * 8 + j;
    float wv = (k < HID) ? wih1[row * HID + k] : whh1[row * HID + k - HID];
    u16 hi = f2bf(wv), lo = f2bf(wv - bf2f(hi));
    int base = W1U + ((nt * KB1 + kb) * 2) * 512;
    pu[base + q] = hi;
    pu[base + 512 + q] = lo;
  } else if (idx < 237568) {               // W_dec: 4nt * 4kb * 512
    int r = idx - 229376;
    int nt = r >> 11, rem = r & 2047;
    int kb = rem >> 9, q = rem & 511, ln = q >> 3, j = q & 7;
    int o = nt * 16 + (ln & 15);
    int k = kb * 32 + (ln >> 4) * 8 + j;
    float wv = wdec[o * HID + k];
    u16 hi = f2bf(wv), lo = f2bf(wv - bf2f(hi));
    int base = WDU + ((nt * KBD + kb) * 2) * 512;
    pu[base + q] = hi;
    pu[base + 512 + q] = lo;
  } else if (idx < 238080) {               // b0 permuted + summed
    int n = idx - 237568;
    int row = ((n >> 4) & 3) * HID + (n >> 6) * 16 + (n & 15);
    pf[B0F + n] = bih0[row] + bhh0[row];
  } else if (idx < 238592) {               // b1 permuted + summed
    int n = idx - 238080;
    int row = ((n >> 4) & 3) * HID + (n >> 6) * 16 + (n & 15);
    pf[B1F + n] = bih1[row] + bhh1[row];
  } else {                                 // b_dec
    int o = idx - 238592;
    pf[BDF + o] = bdec[o];
  }
}

extern "C" void kernel_launch(void* const* d_in, const int* in_sizes, int n_in,
                              void* d_out, int out_size, void* d_ws, size_t ws_size,
                              hipStream_t stream) {
  const float* x    = (const float*)d_in[0];
  const float* wih0 = (const float*)d_in[1];
  const float* whh0 = (const float*)d_in[2];
  const float* bih0 = (const float*)d_in[3];
  const float* bhh0 = (const float*)d_in[4];
  const float* wih1 = (const float*)d_in[5];
  const float* whh1 = (const float*)d_in[6];
  const float* bih1 = (const float*)d_in[7];
  const float* bhh1 = (const float*)d_in[8];
  const float* wdec = (const float*)d_in[9];
  const float* bdec = (const float*)d_in[10];
  float* out = (float*)d_out;

  const int S = in_sizes[0] / (BATCH * INDIM);     // 128
  const int P = out_size / (BATCH * OUTDIM);       // 20

  prepack_kernel<<<(NPACK + 255) / 256, 256, 0, stream>>>(
      wih0, whh0, bih0, bhh0, wih1, whh1, bih1, bhh1, wdec, bdec, d_ws);

  lstm_kernel<<<BATCH / BT, NT, 0, stream>>>(x, d_ws, out, S, P);
}